// Round 10
// baseline (287.762 us; speedup 1.0000x reference)
//
#include <hip/hip_runtime.h>
#include <hip/hip_bf16.h>
#include <hip/hip_fp8.h>

// ---------------------------------------------------------------------------
// GRACE contrastive loss, MI355X.
//  out = mean_k 0.5*(ln d1_k + ln d2_k) - 2*s12[k,k]
// With M=[n1;n2] (24576x256) everything is row sums of exp(M M^T / tau)
// split by j-half, plus diagonal probes. S symmetric -> upper-triangle
// tiles only (R12), with both row-sums and col-sums extracted per tile.
//
// R16: COLUMN-MAJOR WALK, J IN REGISTERS. Diagnosis: FETCH_SIZE 27.7MB =
// 4.6 x Nq(6MB) every round -> TCC(L2) thrashes because Nq > 4MB/XCD and
// co-resident blocks walk DIFFERENT J-windows; stage/loads are served at
// L3 latency (600-900cy) -> the immovable ~45us idle. R15 (direct L2
// loads) made it worse (101us idle). Fix: each block owns a J-tile pair
// (jbig=191-p then jsmall=p, 193 A-tiles total - same slot math) and
// keeps the J-side MFMA fragments in REGISTERS (64 VGPR, ~1 load/block);
// the A-tile is staged to LDS and ALL blocks walk a=0,1,2,... in the
// same order -> co-resident blocks read the same A-tile -> working set
// ~16-80 tiles (0.5-2.5MB) fits L2 -> staging is L2-hit. The nj loop is
// now memory-free (B in regs, aF read once per tile), and only the
// row-sum ATOMICS are deferred past the barrier (shfl reduce is inline;
// R13 showed the cost is the vmcnt(0) drain of pre-barrier atomics).
// Col-sums (j fixed) accumulate in regs across the stripe, flushed <=2x.
// Tripwire: WRITE >> 26MB = spill = experiment invalid.
// ---------------------------------------------------------------------------

#define NROWS 12288
#define TWO_N 24576
#define KDIM 256
#define BM 128
#define BN 128
#define BK 32
#define NTILE 192   /* 24576 / 128 tiles per side */
#define PAIRS 96
#define SLOTS 16
#define FB 48                   /* finalize partial blocks */
#define LOG2E 1.4426950408889634f
#define SIMSCALE 1.6986436f     /* sqrt(2*log2(e)); acc = (1/tau)*log2e*s */
#define LN2F 0.6931471805599453f

#if __has_builtin(__builtin_amdgcn_exp2f)
#define EXP2F(x) __builtin_amdgcn_exp2f(x)
#else
#define EXP2F(x) exp2f(x)
#endif

typedef __bf16 bf16x8 __attribute__((ext_vector_type(8)));
typedef __bf16 bf16x4v __attribute__((ext_vector_type(4)));
typedef float f32x4 __attribute__((ext_vector_type(4)));
typedef int i32x4 __attribute__((ext_vector_type(4)));
typedef int i32x8 __attribute__((ext_vector_type(8)));
typedef unsigned char uchar;

typedef const __attribute__((address_space(1))) void* gptr_t;
typedef __attribute__((address_space(3))) void* lptr_t;

// ======== legacy 128x128 bf16 GEMM core (proj1/proj2 only) ================
__device__ __forceinline__ void stage_slab(const __bf16* g, int row0, int kelem,
                                           __bf16* lds, int w, int l) {
#pragma unroll
  for (int t = 0; t < 2; ++t) {
    int chunk = w * 2 + t;
    int r = chunk * 16 + (l >> 2);
    int c = l & 3;
    int src = c ^ (r & 3);
    const __bf16* ga = g + (size_t)(row0 + r) * KDIM + kelem + src * 8;
    __bf16* la = lds + chunk * 512;
    __builtin_amdgcn_global_load_lds((gptr_t)ga, (lptr_t)la, 16, 0, 0);
  }
}

__device__ __forceinline__ bf16x8 read_frag(const __bf16* lds, int rowbase,
                                            int tile, int l) {
  int r = rowbase + tile * 16 + (l & 15);
  int q = l >> 4;
  int blk = q ^ (r & 3);
  return *(const bf16x8*)(lds + r * 32 + blk * 8);
}

__device__ __forceinline__ void gemm_tile_core(const __bf16* A, int arow0,
                                               const __bf16* B, int brow0,
                                               __bf16* As, __bf16* Bs,
                                               f32x4 (&acc)[4][4], int w, int l) {
  const int warow = (w >> 1) * 64;
  const int wbrow = (w & 1) * 64;
#pragma unroll
  for (int ks = 0; ks < KDIM / BK; ++ks) {
    __syncthreads();
    stage_slab(A, arow0, ks * BK, As, w, l);
    stage_slab(B, brow0, ks * BK, Bs, w, l);
    __syncthreads();
    bf16x8 aF[4], bF[4];
#pragma unroll
    for (int mi = 0; mi < 4; ++mi) aF[mi] = read_frag(As, warow, mi, l);
#pragma unroll
    for (int ni = 0; ni < 4; ++ni) bF[ni] = read_frag(Bs, wbrow, ni, l);
#pragma unroll
    for (int mi = 0; mi < 4; ++mi)
#pragma unroll
      for (int ni = 0; ni < 4; ++ni)
        acc[mi][ni] = __builtin_amdgcn_mfma_f32_16x16x32_bf16(
            aF[mi], bF[ni], acc[mi][ni], 0, 0, 0);
  }
}

// ---------------------------------------------------------------------------
// one launch: cast z1, z2, W1, W2 to bf16 (float4 granules)
__global__ void cast_all_kernel(const float* __restrict__ z1,
                                const float* __restrict__ z2,
                                const float* __restrict__ W1,
                                const float* __restrict__ W2,
                                __bf16* __restrict__ Zb,
                                __bf16* __restrict__ W1b,
                                __bf16* __restrict__ W2b) {
  const int n4z = NROWS * KDIM / 4;  // 786432
  const int n4w = KDIM * KDIM / 4;   // 16384
  int i = blockIdx.x * blockDim.x + threadIdx.x;
  const float* src;
  __bf16* dst;
  int j;
  if (i < n4z) {
    src = z1; dst = Zb; j = i;
  } else if (i < 2 * n4z) {
    src = z2; dst = Zb + (size_t)NROWS * KDIM; j = i - n4z;
  } else if (i < 2 * n4z + n4w) {
    src = W1; dst = W1b; j = i - 2 * n4z;
  } else if (i < 2 * n4z + 2 * n4w) {
    src = W2; dst = W2b; j = i - 2 * n4z - n4w;
  } else {
    return;
  }
  float4 v = *(const float4*)(src + (size_t)j * 4);
  bf16x4v o;
  o[0] = (__bf16)v.x; o[1] = (__bf16)v.y; o[2] = (__bf16)v.z; o[3] = (__bf16)v.w;
  *(bf16x4v*)(dst + (size_t)j * 4) = o;
}

// T = ELU(Z @ W1^T + b1), stored bf16
__global__ __launch_bounds__(256, 2) void proj1_kernel(
    const __bf16* __restrict__ Zb, const __bf16* __restrict__ W1b,
    const float* __restrict__ b1, __bf16* __restrict__ Tb) {
  __shared__ __align__(16) __bf16 As[BM * BK];
  __shared__ __align__(16) __bf16 Bs[BN * BK];
  int w = threadIdx.x >> 6, l = threadIdx.x & 63;
  int i0 = blockIdx.x * BM, j0 = blockIdx.y * BN;
  int warow = (w >> 1) * 64, wbrow = (w & 1) * 64;
  f32x4 acc[4][4] = {};
  gemm_tile_core(Zb, i0, W1b, j0, As, Bs, acc, w, l);
  float bias[4];
#pragma unroll
  for (int ni = 0; ni < 4; ++ni) bias[ni] = b1[j0 + wbrow + ni * 16 + (l & 15)];
#pragma unroll
  for (int mi = 0; mi < 4; ++mi)
#pragma unroll
    for (int ni = 0; ni < 4; ++ni)
#pragma unroll
      for (int v = 0; v < 4; ++v) {
        int row = i0 + warow + mi * 16 + (l >> 4) * 4 + v;
        int col = j0 + wbrow + ni * 16 + (l & 15);
        float x = acc[mi][ni][v] + bias[ni];
        x = x > 0.f ? x : (EXP2F(x * LOG2E) - 1.f);  // ELU
        Tb[(size_t)row * KDIM + col] = (__bf16)x;
      }
}

// H = T @ W2^T + b2 (fp32), plus per-row sum of squares via atomics
__global__ __launch_bounds__(256, 2) void proj2_kernel(
    const __bf16* __restrict__ Tb, const __bf16* __restrict__ W2b,
    const float* __restrict__ b2, float* __restrict__ H,
    float* __restrict__ SS) {
  __shared__ __align__(16) __bf16 As[BM * BK];
  __shared__ __align__(16) __bf16 Bs[BN * BK];
  int w = threadIdx.x >> 6, l = threadIdx.x & 63;
  int i0 = blockIdx.x * BM, j0 = blockIdx.y * BN;
  int warow = (w >> 1) * 64, wbrow = (w & 1) * 64;
  f32x4 acc[4][4] = {};
  gemm_tile_core(Tb, i0, W2b, j0, As, Bs, acc, w, l);
  float bias[4];
#pragma unroll
  for (int ni = 0; ni < 4; ++ni) bias[ni] = b2[j0 + wbrow + ni * 16 + (l & 15)];
  float ss[4][4] = {};
#pragma unroll
  for (int mi = 0; mi < 4; ++mi)
#pragma unroll
    for (int ni = 0; ni < 4; ++ni)
#pragma unroll
      for (int v = 0; v < 4; ++v) {
        int row = i0 + warow + mi * 16 + (l >> 4) * 4 + v;
        int col = j0 + wbrow + ni * 16 + (l & 15);
        float x = acc[mi][ni][v] + bias[ni];
        H[(size_t)row * KDIM + col] = x;
        ss[mi][v] += x * x;
      }
#pragma unroll
  for (int mi = 0; mi < 4; ++mi)
#pragma unroll
    for (int v = 0; v < 4; ++v) {
      float x = ss[mi][v];
      x += __shfl_xor(x, 1, 64);
      x += __shfl_xor(x, 2, 64);
      x += __shfl_xor(x, 4, 64);
      x += __shfl_xor(x, 8, 64);
      if ((l & 15) == 0)
        atomicAdd(&SS[i0 + warow + mi * 16 + (l >> 4) * 4 + v], x);
    }
}

// pack 4 floats -> 4 fp8 e4m3 bytes
__device__ __forceinline__ unsigned int pack4_fp8(float a, float b, float c,
                                                  float d) {
#if __has_builtin(__builtin_amdgcn_cvt_pk_fp8_f32)
  int v = 0;
  v = __builtin_amdgcn_cvt_pk_fp8_f32(a, b, v, false);
  v = __builtin_amdgcn_cvt_pk_fp8_f32(c, d, v, true);
  return (unsigned int)v;
#else
  __hip_fp8_e4m3 qa(a), qb(b), qc(c), qd(d);
  return (unsigned int)qa.__x | ((unsigned int)qb.__x << 8) |
         ((unsigned int)qc.__x << 16) | ((unsigned int)qd.__x << 24);
#endif
}

// Nq = fp8(H * rsqrt(SS[row]) * SIMSCALE) — 8 elements per thread.
// SIMSCALE folds the (1/tau)*log2(e) exponent scale into the data:
// dot(Nq_i, Nq_j) = 2.8854 * cos_ij, so exp2(acc) = exp(cos/tau).
__global__ void norm_kernel(const float* __restrict__ H,
                            const float* __restrict__ SS,
                            uchar* __restrict__ Nq) {
  int i = blockIdx.x * blockDim.x + threadIdx.x;
  size_t idx = (size_t)i * 8;
  if (idx >= (size_t)TWO_N * KDIM) return;
  int row = (int)(idx >> 8);
  float inv = rsqrtf(SS[row]) * SIMSCALE;
  float4 h0 = *(const float4*)(H + idx);
  float4 h1 = *(const float4*)(H + idx + 4);
  uint2 o;
  o.x = pack4_fp8(h0.x * inv, h0.y * inv, h0.z * inv, h0.w * inv);
  o.y = pack4_fp8(h1.x * inv, h1.y * inv, h1.z * inv, h1.w * inv);
  *(uint2*)(Nq + idx) = o;
}

// ======== R16 sim kernel: column-major walk, J in registers ================
// Block b: pair p = b>>4, slot s = b&15. jbig = 191-p, len1 = 192-p.
//   F in [0, len1): A-tile a = F, J-tile jt = jbig  (stripe 1)
//   F in [len1,193): a = F - len1, jt = p           (stripe 2)
// a <= jt always; diag tiles at F = len1-1 (a=jbig) and F = 192 (a=p).
// All blocks walk a = 0,1,2,... => co-resident blocks (same slot window)
// stage the SAME A-tile => L2-resident staging. J-side fragments bF[4][2]
// live in registers per stripe. Per tile: stage(f+1) async; aF from LDS
// (16 ds_read_b128, one wait region); nj-loop pure regs (8 MFMA + exps);
// row-sums shfl-reduced in place at tile end, ATOMICS deferred past the
// next barrier; col-sums accumulate in regs, flushed on half-cross /
// stripe switch.
__global__ __launch_bounds__(256, 2) void sim_kernel(
    const uchar* __restrict__ Nq, float* __restrict__ Rlow,
    float* __restrict__ Rhigh, float* __restrict__ Dsame,
    float* __restrict__ Dcross) {
  __shared__ __align__(16) uchar As[2][BM * KDIM];  // A-tile dbuf, 2 x 32KB
  int tid = threadIdx.x;
  int w = tid >> 6, l = tid & 63;
  int q = l >> 4;
  int rx = l & 15;
  int b = blockIdx.x;
  int p = b >> 4;              // pair 0..95
  int s = b & 15;              // slot 0..15
  const int jbig = NTILE - 1 - p;
  const int len1 = NTILE - p;  // stripe-1 length
  int fstart = (s == 0) ? 0 : 13 + (s - 1) * 12;
  int fend = fstart + ((s == 0) ? 13 : 12);
  int warow = (w >> 1) * 64;   // A rows (i-side) of this wave
  int wbcol = (w & 1) * 64;    // J rows (col-side) of this wave

  // staging offsets (XOR swizzle: LDS slot c of row r holds block c^(r&15))
  unsigned off0[8];
#pragma unroll
  for (int t = 0; t < 8; ++t) {
    int ch = w * 8 + t;            // chunk 0..31 (1KB each)
    int r = ch * 4 + q;            // row 0..127
    int src = rx ^ (r & 15);
    off0[t] = (unsigned)(r * KDIM + src * 16);
  }
  auto a_of = [&](int F) { return (F < len1) ? F : F - len1; };
  auto j_of = [&](int F) { return (F < len1) ? jbig : p; };

  auto stage = [&](int F, int bi) {
    unsigned jo = (unsigned)(a_of(F) * (BM * KDIM));
#pragma unroll
    for (int t = 0; t < 8; ++t) {
      const uchar* ga = Nq + (size_t)(jo + off0[t]);
      uchar* la = As[bi] + (w * 8 + t) * 1024;  // wave-uniform base
      __builtin_amdgcn_global_load_lds((gptr_t)ga, (lptr_t)la, 16, 0, 0);
    }
  };

  // J-side fragments in registers (constant per stripe): bF[nj][hf]
  i32x8 bF[4][2];
  auto load_bF = [&](int jt) {
#pragma unroll
    for (int nj = 0; nj < 4; ++nj) {
      const uchar* bp =
          Nq + (size_t)(jt * BM + wbcol + nj * 16 + rx) * KDIM + q * 32;
      bF[nj][0] = *(const i32x8*)(bp);
      bF[nj][1] = *(const i32x8*)(bp + 128);
    }
  };

  // lane-constant LDS read offsets for aF (same swizzle math as R13)
  int rdo[2][2];
#pragma unroll
  for (int hf = 0; hf < 2; ++hf) {
    int kb = hf * 8 + 2 * q;
    rdo[hf][0] = (kb ^ rx) << 4;
    rdo[hf][1] = ((kb + 1) ^ rx) << 4;
  }

  f32x4 rs4[4] = {};  // row sums of current tile (reduced in place at end)
  f32x4 cs4[4] = {};  // col partials, accumulated across the stripe
  int rpend = 0, rBase = 0;
  float* rP = nullptr;

  // atomic-only flush of the (already shfl-reduced) pending row sums
  auto flushrs_atomic = [&]() {
    if (rx == 0) {
#pragma unroll
      for (int mi = 0; mi < 4; ++mi)
#pragma unroll
        for (int v = 0; v < 4; ++v)
          atomicAdd(&rP[rBase + warow + mi * 16 + q * 4 + v], rs4[mi][v]);
    }
#pragma unroll
    for (int mi = 0; mi < 4; ++mi)
      rs4[mi] = (f32x4){0.f, 0.f, 0.f, 0.f};
    rpend = 0;
  };
  auto flushcs = [&](int jt, int h) {
    float* R = h ? Rhigh : Rlow;
#pragma unroll
    for (int nj = 0; nj < 4; ++nj) {
      float c = (cs4[nj][0] + cs4[nj][1]) + (cs4[nj][2] + cs4[nj][3]);
      c += __shfl_xor(c, 16, 64);
      c += __shfl_xor(c, 32, 64);
      if (q == 0)
        atomicAdd(&R[jt * BM + wbcol + nj * 16 + rx], c);
      cs4[nj] = (f32x4){0.f, 0.f, 0.f, 0.f};
    }
  };

  const f32x4 Z4 = {0.f, 0.f, 0.f, 0.f};

  int jcur = j_of(fstart);
  int csh = (a_of(fstart) >= NTILE / 2) ? 1 : 0;
  load_bF(jcur);
  stage(fstart, 0);  // prologue

  for (int f = fstart; f < fend; ++f) {
    int bi = (f - fstart) & 1;
    __syncthreads();                        // stage(f) done; prev reads done
    if (f + 1 < fend) stage(f + 1, bi ^ 1); // drains at NEXT barrier
    if (rpend) flushrs_atomic();            // atomics drain a full tile later

    int a = a_of(f), jt = j_of(f);
    if (jt != jcur) {            // stripe switch (<=1 per block)
      flushcs(jcur, csh);
      load_bF(jt);
      jcur = jt;
      csh = 0;                   // new stripe starts at a = 0 (low half)
    }
    int ha = (a >= NTILE / 2) ? 1 : 0;
    if (ha != csh) { flushcs(jcur, csh); csh = ha; }

    bool dsame = (a == jt);
    bool dcross = (jt == a + NTILE / 2);

    // ---- aF from LDS (one wait region per tile) ----
    const uchar* aL = As[bi] + (size_t)(warow + rx) * KDIM;
    i32x8 aF[4][2];
#pragma unroll
    for (int mi = 0; mi < 4; ++mi) {
      const int mo = mi * 4096;
      aF[mi][0] = __builtin_shufflevector(
          *(const i32x4*)(aL + mo + rdo[0][0]),
          *(const i32x4*)(aL + mo + rdo[0][1]), 0, 1, 2, 3, 4, 5, 6, 7);
      aF[mi][1] = __builtin_shufflevector(
          *(const i32x4*)(aL + mo + rdo[1][0]),
          *(const i32x4*)(aL + mo + rdo[1][1]), 0, 1, 2, 3, 4, 5, 6, 7);
    }

#pragma unroll
    for (int nj = 0; nj < 4; ++nj) {
      f32x4 acc[4];
#pragma unroll
      for (int mi = 0; mi < 4; ++mi)
        acc[mi] = __builtin_amdgcn_mfma_scale_f32_16x16x128_f8f6f4(
            aF[mi][0], bF[nj][0], Z4, 0, 0, 0, 0x7F7F7F7F, 0, 0x7F7F7F7F);
#pragma unroll
      for (int mi = 0; mi < 4; ++mi)
        acc[mi] = __builtin_amdgcn_mfma_scale_f32_16x16x128_f8f6f4(
            aF[mi][1], bF[nj][1], acc[mi], 0, 0, 0, 0x7F7F7F7F, 0, 0x7F7F7F7F);

      if (dsame | dcross) {       // wave-uniform, rare; uses raw acc
        float* D = dsame ? Dsame : Dcross;
#pragma unroll
        for (int mi = 0; mi < 4; ++mi)
#pragma unroll
          for (int v = 0; v < 4; ++v) {
            int li = warow + mi * 16 + q * 4 + v;
            int lj = wbcol + nj * 16 + rx;
            if (li == lj) D[a * BM + li] = acc[mi][v];
          }
      }

      // exp in place; row sums always; col sums except on diag tile
#pragma unroll
      for (int mi = 0; mi < 4; ++mi) {
        f32x4 e4;
        e4[0] = EXP2F(acc[mi][0]);
        e4[1] = EXP2F(acc[mi][1]);
        e4[2] = EXP2F(acc[mi][2]);
        e4[3] = EXP2F(acc[mi][3]);
        acc[mi] = e4;
        rs4[mi] += e4;
      }
      if (!dsame)
        cs4[nj] += (acc[0] + acc[1]) + (acc[2] + acc[3]);
    }

    // in-place shfl reduce of this tile's row sums (pure DPP, no memory);
    // the atomicAdd is deferred until after the next barrier.
#pragma unroll
    for (int mi = 0; mi < 4; ++mi)
#pragma unroll
      for (int v = 0; v < 4; ++v) {
        float x = rs4[mi][v];
        x += __shfl_xor(x, 1, 64);
        x += __shfl_xor(x, 2, 64);
        x += __shfl_xor(x, 4, 64);
        x += __shfl_xor(x, 8, 64);
        rs4[mi][v] = x;
      }
    rP = (jt >= NTILE / 2) ? Rhigh : Rlow;
    rBase = a * BM;
    rpend = 1;
  }

  if (rpend) flushrs_atomic();  // last tile's row sums
  flushcs(jcur, csh);           // final col-sum flush
}

// Dsame/Dcross hold acc = (1/tau)*log2e * s. exp(s/tau) = exp2(acc);
// -2*s = -ln2 * acc.  48 blocks x 256 threads = 12288 rows exactly.
__global__ void finalize1_kernel(const float* __restrict__ Rlow,
                                 const float* __restrict__ Rhigh,
                                 const float* __restrict__ Dsame,
                                 const float* __restrict__ Dcross,
                                 float* __restrict__ partial) {
  __shared__ float red[256];
  int k = blockIdx.x * 256 + threadIdx.x;
  float d1 = Rlow[k] + Rhigh[k] - EXP2F(Dsame[k]);
  float d2 = Rhigh[NROWS + k] + Rlow[NROWS + k] - EXP2F(Dsame[NROWS + k]);
  float acc = 0.5f * (logf(d1) + logf(d2)) - LN2F * Dcross[k];
  red[threadIdx.x] = acc;
  __syncthreads();
  for (int s = 128; s > 0; s >>= 1) {
    if (threadIdx.x < s) red[threadIdx.x] += red[threadIdx.x + s];
    __syncthreads();
  }
  if (threadIdx.x == 0) partial[blockIdx.x] = red[0];
}

__global__ void finalize2_kernel(const float* __restrict__ partial,
                                 float* __restrict__ out) {
  float x = (threadIdx.x < FB) ? partial[threadIdx.x] : 0.f;
#pragma unroll
  for (int s = 32; s > 0; s >>= 1) x += __shfl_down(x, s, 64);
  if (threadIdx.x == 0) out[0] = x / (float)NROWS;
}

// ---------------------------------------------------------------------------
extern "C" void kernel_launch(void* const* d_in, const int* in_sizes, int n_in,
                              void* d_out, int out_size, void* d_ws,
                              size_t ws_size, hipStream_t stream) {
  const float* z1 = (const float*)d_in[0];
  const float* z2 = (const float*)d_in[1];
  const float* W1 = (const float*)d_in[2];
  const float* b1 = (const float*)d_in[3];
  const float* W2 = (const float*)d_in[4];
  const float* b2 = (const float*)d_in[5];
  float* out = (float*)d_out;

  char* ws = (char*)d_ws;
  size_t off = 0;
  auto alloc = [&](size_t bytes) -> void* {
    void* p = ws + off;
    off += (bytes + 255) & ~(size_t)255;
    return p;
  };
  __bf16* Zb   = (__bf16*)alloc((size_t)TWO_N * KDIM * 2); // reused as Nq
  __bf16* W1b  = (__bf16*)alloc((size_t)KDIM * KDIM * 2);
  __bf16* W2b  = (__bf16*)alloc((size_t)KDIM * KDIM * 2);
  __bf16* Tb   = (__bf16*)alloc((size_t)TWO_N * KDIM * 2);
  float*  H    = (float*)alloc((size_t)TWO_N * KDIM * 4);
  float*  SS   = (float*)alloc((size_t)TWO_N * 4);   // SS,Rlow,Rhigh
  float*  Rlow = (float*)alloc((size_t)TWO_N * 4);   //  contiguous
  float*  Rhigh= (float*)alloc((size_t)TWO_N * 4);   //  (one memset)
  float*  Dsame= (float*)alloc((size_t)TWO_N * 4);
  float*  Dcross=(float*)alloc((size_t)NROWS * 4);
  float*  partial=(float*)alloc((size_t)FB * 4);
  uchar*  Nq = (uchar*)Zb;  // Zb dead after proj1; fp8 fits in its footprint

  // SS/Rlow/Rhigh are adjacent 256-aligned allocations of TWO_N*4 bytes
  hipMemsetAsync(SS, 0, (size_t)3 * TWO_N * 4, stream);

  int n4z = NROWS * KDIM / 4;   // 786432
  int n4w = KDIM * KDIM / 4;    // 16384
  int n4all = 2 * n4z + 2 * n4w;
  cast_all_kernel<<<(n4all + 255) / 256, 256, 0, stream>>>(z1, z2, W1, W2, Zb,
                                                           W1b, W2b);

  proj1_kernel<<<dim3(TWO_N / BM, KDIM / BN), 256, 0, stream>>>(Zb, W1b, b1, Tb);
  proj2_kernel<<<dim3(TWO_N / BM, KDIM / BN), 256, 0, stream>>>(Tb, W2b, b2, H, SS);

  int n8n = TWO_N * KDIM / 8;   // 786432
  norm_kernel<<<(n8n + 255) / 256, 256, 0, stream>>>(H, SS, Nq);

  sim_kernel<<<PAIRS * SLOTS, 256, 0, stream>>>(Nq, Rlow, Rhigh, Dsame,
                                                Dcross);
  finalize1_kernel<<<FB, 256, 0, stream>>>(Rlow, Rhigh, Dsame, Dcross, partial);
  finalize2_kernel<<<1, 64, 0, stream>>>(partial, out);
}

// Round 11
// 216.401 us; speedup vs baseline: 1.3298x; 1.3298x over previous
//
#include <hip/hip_runtime.h>
#include <hip/hip_bf16.h>
#include <hip/hip_fp8.h>

// ---------------------------------------------------------------------------
// GRACE contrastive loss, MI355X.
//  out = mean_k 0.5*(ln d1_k + ln d2_k) - 2*s12[k,k]
// With M=[n1;n2] (24576x256) everything is row sums of exp(M M^T / tau)
// split by j-half, plus diagonal probes. S symmetric -> upper-triangle
// tiles only, row-sums + col-sums per tile (R12), col-sums deferred one
// tile (R13).
//
// R17: sim REVERTED to R13 verbatim (122.8us, best). Six structural
// attempts on sim's idle (R8/R10/R11/R14/R15/R16) were null or worse;
// R16 confirmed the arch-VGPR cap is ~half the launch-bounds budget
// ((256,2) -> ~124), so register-resident B is impossible at this shape.
// This round attacks the OTHER 103.6us: proj2+norm FUSED. proj2 becomes
// 64-row x full-256-col blocks (grid 384, 4 waves of 64x64): each block
// owns complete H rows -> SS via shfl + small LDS cross-wave reduce (no
// atomics, no SS buffer/memset), normalize + fp8-quantize in-register,
// repack via LDS, write Nq directly. Eliminates H (50MB round trip), SS,
// and the norm launch. K-loop register footprint = old proj2 (~120).
// ---------------------------------------------------------------------------

#define NROWS 12288
#define TWO_N 24576
#define KDIM 256
#define BM 128
#define BN 128
#define BK 32
#define NTILE 192   /* 24576 / 128 row-tiles */
#define PAIRS 96
#define SLOTS 16
#define FB 48                   /* finalize partial blocks */
#define LOG2E 1.4426950408889634f
#define SIMSCALE 1.6986436f     /* sqrt(2*log2(e)); acc = (1/tau)*log2e*s */
#define LN2F 0.6931471805599453f

#if __has_builtin(__builtin_amdgcn_exp2f)
#define EXP2F(x) __builtin_amdgcn_exp2f(x)
#else
#define EXP2F(x) exp2f(x)
#endif

typedef __bf16 bf16x8 __attribute__((ext_vector_type(8)));
typedef __bf16 bf16x4v __attribute__((ext_vector_type(4)));
typedef float f32x4 __attribute__((ext_vector_type(4)));
typedef int i32x4 __attribute__((ext_vector_type(4)));
typedef int i32x8 __attribute__((ext_vector_type(8)));
typedef unsigned char uchar;

typedef const __attribute__((address_space(1))) void* gptr_t;
typedef __attribute__((address_space(3))) void* lptr_t;

// ======== 128x128 bf16 GEMM core (proj1) ==================================
__device__ __forceinline__ void stage_slab(const __bf16* g, int row0, int kelem,
                                           __bf16* lds, int w, int l) {
#pragma unroll
  for (int t = 0; t < 2; ++t) {
    int chunk = w * 2 + t;
    int r = chunk * 16 + (l >> 2);
    int c = l & 3;
    int src = c ^ (r & 3);
    const __bf16* ga = g + (size_t)(row0 + r) * KDIM + kelem + src * 8;
    __bf16* la = lds + chunk * 512;
    __builtin_amdgcn_global_load_lds((gptr_t)ga, (lptr_t)la, 16, 0, 0);
  }
}

__device__ __forceinline__ bf16x8 read_frag(const __bf16* lds, int rowbase,
                                            int tile, int l) {
  int r = rowbase + tile * 16 + (l & 15);
  int q = l >> 4;
  int blk = q ^ (r & 3);
  return *(const bf16x8*)(lds + r * 32 + blk * 8);
}

__device__ __forceinline__ void gemm_tile_core(const __bf16* A, int arow0,
                                               const __bf16* B, int brow0,
                                               __bf16* As, __bf16* Bs,
                                               f32x4 (&acc)[4][4], int w, int l) {
  const int warow = (w >> 1) * 64;
  const int wbrow = (w & 1) * 64;
#pragma unroll
  for (int ks = 0; ks < KDIM / BK; ++ks) {
    __syncthreads();
    stage_slab(A, arow0, ks * BK, As, w, l);
    stage_slab(B, brow0, ks * BK, Bs, w, l);
    __syncthreads();
    bf16x8 aF[4], bF[4];
#pragma unroll
    for (int mi = 0; mi < 4; ++mi) aF[mi] = read_frag(As, warow, mi, l);
#pragma unroll
    for (int ni = 0; ni < 4; ++ni) bF[ni] = read_frag(Bs, wbrow, ni, l);
#pragma unroll
    for (int mi = 0; mi < 4; ++mi)
#pragma unroll
      for (int ni = 0; ni < 4; ++ni)
        acc[mi][ni] = __builtin_amdgcn_mfma_f32_16x16x32_bf16(
            aF[mi], bF[ni], acc[mi][ni], 0, 0, 0);
  }
}

// ---------------------------------------------------------------------------
// one launch: cast z1, z2, W1, W2 to bf16 (float4 granules)
__global__ void cast_all_kernel(const float* __restrict__ z1,
                                const float* __restrict__ z2,
                                const float* __restrict__ W1,
                                const float* __restrict__ W2,
                                __bf16* __restrict__ Zb,
                                __bf16* __restrict__ W1b,
                                __bf16* __restrict__ W2b) {
  const int n4z = NROWS * KDIM / 4;  // 786432
  const int n4w = KDIM * KDIM / 4;   // 16384
  int i = blockIdx.x * blockDim.x + threadIdx.x;
  const float* src;
  __bf16* dst;
  int j;
  if (i < n4z) {
    src = z1; dst = Zb; j = i;
  } else if (i < 2 * n4z) {
    src = z2; dst = Zb + (size_t)NROWS * KDIM; j = i - n4z;
  } else if (i < 2 * n4z + n4w) {
    src = W1; dst = W1b; j = i - 2 * n4z;
  } else if (i < 2 * n4z + 2 * n4w) {
    src = W2; dst = W2b; j = i - 2 * n4z - n4w;
  } else {
    return;
  }
  float4 v = *(const float4*)(src + (size_t)j * 4);
  bf16x4v o;
  o[0] = (__bf16)v.x; o[1] = (__bf16)v.y; o[2] = (__bf16)v.z; o[3] = (__bf16)v.w;
  *(bf16x4v*)(dst + (size_t)j * 4) = o;
}

// T = ELU(Z @ W1^T + b1), stored bf16
__global__ __launch_bounds__(256, 2) void proj1_kernel(
    const __bf16* __restrict__ Zb, const __bf16* __restrict__ W1b,
    const float* __restrict__ b1, __bf16* __restrict__ Tb) {
  __shared__ __align__(16) __bf16 As[BM * BK];
  __shared__ __align__(16) __bf16 Bs[BN * BK];
  int w = threadIdx.x >> 6, l = threadIdx.x & 63;
  int i0 = blockIdx.x * BM, j0 = blockIdx.y * BN;
  int warow = (w >> 1) * 64, wbrow = (w & 1) * 64;
  f32x4 acc[4][4] = {};
  gemm_tile_core(Zb, i0, W1b, j0, As, Bs, acc, w, l);
  float bias[4];
#pragma unroll
  for (int ni = 0; ni < 4; ++ni) bias[ni] = b1[j0 + wbrow + ni * 16 + (l & 15)];
#pragma unroll
  for (int mi = 0; mi < 4; ++mi)
#pragma unroll
    for (int ni = 0; ni < 4; ++ni)
#pragma unroll
      for (int v = 0; v < 4; ++v) {
        int row = i0 + warow + mi * 16 + (l >> 4) * 4 + v;
        int col = j0 + wbrow + ni * 16 + (l & 15);
        float x = acc[mi][ni][v] + bias[ni];
        x = x > 0.f ? x : (EXP2F(x * LOG2E) - 1.f);  // ELU
        Tb[(size_t)row * KDIM + col] = (__bf16)x;
      }
}

// fp8 e4m3 byte via the HW cvt (same rounding as the old norm kernel)
__device__ __forceinline__ uchar fp8_byte(float x) {
#if __has_builtin(__builtin_amdgcn_cvt_pk_fp8_f32)
  int v = __builtin_amdgcn_cvt_pk_fp8_f32(x, 0.f, 0, false);
  return (uchar)(v & 0xFF);
#else
  __hip_fp8_e4m3 qv(x);
  return qv.__x;
#endif
}

// ======== R17 fused proj2 + norm ===========================================
// Block = 64 rows x all 256 cols of H (grid 384, 256 thr, 4 waves of
// 64x64). H never hits memory: x = T@W2^T + b2 stays in acc; SS per row
// via shfl(1,2,4,8) + ssred[4][64] cross-wave LDS reduce; inv = rsqrt *
// SIMSCALE; quantize to fp8 into qbuf (LDS repack) and store Nq as uint2.
__global__ __launch_bounds__(256, 2) void proj2norm_kernel(
    const __bf16* __restrict__ Tb, const __bf16* __restrict__ W2b,
    const float* __restrict__ b2, uchar* __restrict__ Nq) {
  __shared__ __align__(16) __bf16 As[64 * BK];     // 4 KB
  __shared__ __align__(16) __bf16 Bs[KDIM * BK];   // 16 KB
  __shared__ float ssred[4][64];                   // 1 KB
  __shared__ float invred[64];
  __shared__ __align__(8) uchar qbuf[64 * KDIM];   // 16 KB
  int tid = threadIdx.x;
  int w = tid >> 6, l = tid & 63;
  int q = l >> 4, rx = l & 15;
  int i0 = blockIdx.x * 64;
  int wbcol = w * 64;   // this wave's 64 output cols; all waves share rows

  f32x4 acc[4][4] = {};
#pragma unroll
  for (int ks = 0; ks < KDIM / BK; ++ks) {
    __syncthreads();
    // stage 20 chunks of 16 rows x 32 cols (A: 4 chunks, B: 16), 5/wave
#pragma unroll
    for (int t = 0; t < 5; ++t) {
      int c = w * 5 + t;           // wave-uniform 0..19
      int rr = l >> 2, c2 = l & 3;
      if (c < 4) {
        int r = c * 16 + rr;
        int src = c2 ^ (r & 3);
        const __bf16* ga = Tb + (size_t)(i0 + r) * KDIM + ks * BK + src * 8;
        __builtin_amdgcn_global_load_lds((gptr_t)ga, (lptr_t)(As + c * 512),
                                         16, 0, 0);
      } else {
        int cc = c - 4;
        int r = cc * 16 + rr;
        int src = c2 ^ (r & 3);
        const __bf16* ga = W2b + (size_t)r * KDIM + ks * BK + src * 8;
        __builtin_amdgcn_global_load_lds((gptr_t)ga, (lptr_t)(Bs + cc * 512),
                                         16, 0, 0);
      }
    }
    __syncthreads();
    bf16x8 aF[4], bF[4];
#pragma unroll
    for (int mi = 0; mi < 4; ++mi) aF[mi] = read_frag(As, 0, mi, l);
#pragma unroll
    for (int ni = 0; ni < 4; ++ni) bF[ni] = read_frag(Bs, wbcol, ni, l);
#pragma unroll
    for (int mi = 0; mi < 4; ++mi)
#pragma unroll
      for (int ni = 0; ni < 4; ++ni)
        acc[mi][ni] = __builtin_amdgcn_mfma_f32_16x16x32_bf16(
            aF[mi], bF[ni], acc[mi][ni], 0, 0, 0);
  }

  // ---- bias + per-row sum of squares (this wave's 64-col band) ----
  float bias[4];
#pragma unroll
  for (int ni = 0; ni < 4; ++ni) bias[ni] = b2[wbcol + ni * 16 + rx];
  float ss[4][4] = {};
#pragma unroll
  for (int mi = 0; mi < 4; ++mi)
#pragma unroll
    for (int ni = 0; ni < 4; ++ni)
#pragma unroll
      for (int v = 0; v < 4; ++v) {
        float x = acc[mi][ni][v] + bias[ni];
        acc[mi][ni][v] = x;
        ss[mi][v] += x * x;
      }
#pragma unroll
  for (int mi = 0; mi < 4; ++mi)
#pragma unroll
    for (int v = 0; v < 4; ++v) {
      float x = ss[mi][v];
      x += __shfl_xor(x, 1, 64);
      x += __shfl_xor(x, 2, 64);
      x += __shfl_xor(x, 4, 64);
      x += __shfl_xor(x, 8, 64);
      if (rx == 0) ssred[w][mi * 16 + q * 4 + v] = x;  // band partial
    }
  __syncthreads();
  if (tid < 64)
    invred[tid] = rsqrtf(ssred[0][tid] + ssred[1][tid] + ssred[2][tid] +
                         ssred[3][tid]) * SIMSCALE;
  __syncthreads();

  // ---- quantize into qbuf (LDS), then coalesced uint2 store to Nq ----
#pragma unroll
  for (int mi = 0; mi < 4; ++mi)
#pragma unroll
    for (int v = 0; v < 4; ++v) {
      int row = mi * 16 + q * 4 + v;
      float iv = invred[row];
#pragma unroll
      for (int ni = 0; ni < 4; ++ni)
        qbuf[row * KDIM + wbcol + ni * 16 + rx] =
            fp8_byte(acc[mi][ni][v] * iv);
    }
  __syncthreads();
  size_t base = (size_t)i0 * KDIM;
#pragma unroll
  for (int it = 0; it < 8; ++it) {
    int idx = it * 2048 + tid * 8;
    *(uint2*)(Nq + base + idx) = *(const uint2*)(qbuf + idx);
  }
}

// ======== R13 sim kernel (verbatim — best: 122.8us) ========================
__global__ __launch_bounds__(256, 2) void sim_kernel(
    const uchar* __restrict__ Nq, float* __restrict__ Rlow,
    float* __restrict__ Rhigh, float* __restrict__ Dsame,
    float* __restrict__ Dcross) {
  __shared__ __align__(16) uchar Bs[2][BM * KDIM];  // 2 x 32KB
  int tid = threadIdx.x;
  int w = tid >> 6, l = tid & 63;
  int q = l >> 4;
  int rx = l & 15;
  int b = blockIdx.x;
  int p = b >> 4;              // pair index 0..95
  int s = b & 15;              // slot within pair
  const int I1 = p, I2 = NTILE - 1 - p;
  const int L1 = NTILE - I1;   // seg1 length
  int fstart = (s == 0) ? 0 : 13 + (s - 1) * 12;
  int fend = fstart + ((s == 0) ? 13 : 12);
  int warow = (w >> 1) * 64;   // A rows of this wave
  int wbcol = (w & 1) * 64;    // B cols of this wave

  unsigned off0[8];
#pragma unroll
  for (int t = 0; t < 8; ++t) {
    int ch = w * 8 + t;
    int r = ch * 4 + (l >> 4);
    int c = l & 15;
    int src = c ^ (r & 15);
    off0[t] = (unsigned)(r * KDIM + src * 16);
  }
  auto jtile_of = [&](int F) { return (F < L1) ? (I1 + F) : (F - 1); };
  auto atile_of = [&](int F) { return (F < L1) ? I1 : I2; };

  auto stage = [&](int F, int bi) {
    unsigned jo = (unsigned)(jtile_of(F) * (BM * KDIM));
#pragma unroll
    for (int t = 0; t < 8; ++t) {
      const uchar* ga = Nq + (size_t)(jo + off0[t]);
      uchar* la = Bs[bi] + (w * 8 + t) * 1024;
      __builtin_amdgcn_global_load_lds((gptr_t)ga, (lptr_t)la, 16, 0, 0);
    }
  };

  i32x8 aF[4][2];
  auto load_aF = [&](int Atile) {
#pragma unroll
    for (int mi = 0; mi < 4; ++mi) {
      const uchar* ap = Nq +
          (size_t)(Atile * BM + warow + mi * 16 + rx) * KDIM + q * 32;
#pragma unroll
      for (int hf = 0; hf < 2; ++hf)
        aF[mi][hf] = *(const i32x8*)(ap + hf * 128);
    }
  };

  int rdo[2][2];
#pragma unroll
  for (int hf = 0; hf < 2; ++hf) {
    int kb = hf * 8 + 2 * q;
    rdo[hf][0] = (kb ^ rx) << 4;
    rdo[hf][1] = ((kb + 1) ^ rx) << 4;
  }

  f32x4 rs4[4] = {};
  f32x4 cs4[4];
  int pend = 0;
  float* pendR = nullptr;
  int pendBase = 0;

  auto flushrs = [&](int Atile, int h) {
    float* R = h ? Rhigh : Rlow;
#pragma unroll
    for (int mi = 0; mi < 4; ++mi)
#pragma unroll
      for (int v = 0; v < 4; ++v) {
        float x = rs4[mi][v];
        x += __shfl_xor(x, 1, 64);
        x += __shfl_xor(x, 2, 64);
        x += __shfl_xor(x, 4, 64);
        x += __shfl_xor(x, 8, 64);
        if (rx == 0)
          atomicAdd(&R[Atile * BM + warow + mi * 16 + q * 4 + v], x);
        rs4[mi][v] = 0.f;
      }
  };
  auto flushcs = [&]() {
#pragma unroll
    for (int nj = 0; nj < 4; ++nj) {
      float c = (cs4[nj][0] + cs4[nj][1]) + (cs4[nj][2] + cs4[nj][3]);
      c += __shfl_xor(c, 16, 64);
      c += __shfl_xor(c, 32, 64);
      if (q == 0)
        atomicAdd(&pendR[pendBase + wbcol + nj * 16 + rx], c);
    }
    pend = 0;
  };

  const f32x4 Z4 = {0.f, 0.f, 0.f, 0.f};

  int Aprev = atile_of(fstart);
  int hprev = (jtile_of(fstart) >= NTILE / 2) ? 1 : 0;
  load_aF(Aprev);
  stage(fstart, 0);

  for (int f = fstart; f < fend; ++f) {
    int bi = (f - fstart) & 1;
    __syncthreads();
    if (f + 1 < fend) stage(f + 1, bi ^ 1);
    if (pend) flushcs();

    int Atile = atile_of(f);
    int Jt = jtile_of(f);
    int h = (Jt >= NTILE / 2) ? 1 : 0;
    if (Atile != Aprev) {
      flushrs(Aprev, hprev);
      load_aF(Atile);
      Aprev = Atile;
      hprev = h;
    } else if (h != hprev) {
      flushrs(Aprev, hprev);
      hprev = h;
    }

    bool dsame = (Jt == Atile);
    bool dcross = (Jt == Atile + NTILE / 2);
    float* Rcol = (Atile >= NTILE / 2) ? Rhigh : Rlow;

    const uchar* bL = Bs[bi] + (size_t)(wbcol + rx) * KDIM;
    const uchar* p00 = bL + rdo[0][0];
    const uchar* p01 = bL + rdo[0][1];
    const uchar* p10 = bL + rdo[1][0];
    const uchar* p11 = bL + rdo[1][1];

#pragma unroll
    for (int nj = 0; nj < 4; ++nj) {
      const int no = nj * 4096;
      i32x8 bF0 = __builtin_shufflevector(*(const i32x4*)(p00 + no),
                                          *(const i32x4*)(p01 + no),
                                          0, 1, 2, 3, 4, 5, 6, 7);
      i32x8 bF1 = __builtin_shufflevector(*(const i32x4*)(p10 + no),
                                          *(const i32x4*)(p11 + no),
                                          0, 1, 2, 3, 4, 5, 6, 7);
      f32x4 acc[4];
#pragma unroll
      for (int mi = 0; mi < 4; ++mi)
        acc[mi] = __builtin_amdgcn_mfma_scale_f32_16x16x128_f8f6f4(
            aF[mi][0], bF0, Z4, 0, 0, 0, 0x7F7F7F7F, 0, 0x7F7F7F7F);
#pragma unroll
      for (int mi = 0; mi < 4; ++mi)
        acc[mi] = __builtin_amdgcn_mfma_scale_f32_16x16x128_f8f6f4(
            aF[mi][1], bF1, acc[mi], 0, 0, 0, 0x7F7F7F7F, 0, 0x7F7F7F7F);
      float cs = 0.f;
#pragma unroll
      for (int mi = 0; mi < 4; ++mi) {
        f32x4 e4;
        e4[0] = EXP2F(acc[mi][0]);
        e4[1] = EXP2F(acc[mi][1]);
        e4[2] = EXP2F(acc[mi][2]);
        e4[3] = EXP2F(acc[mi][3]);
        rs4[mi] += e4;
        cs4[nj] = (mi == 0) ? e4 : (cs4[nj] + e4);
      }
      (void)cs;

      if (dsame | dcross) {
        float* D = dsame ? Dsame : Dcross;
#pragma unroll
        for (int mi = 0; mi < 4; ++mi)
#pragma unroll
          for (int v = 0; v < 4; ++v) {
            int li = warow + mi * 16 + q * 4 + v;
            int lj = wbcol + nj * 16 + rx;
            if (li == lj) D[Atile * BM + li] = acc[mi][v];
          }
      }
    }

    if (!dsame) {
      pend = 1;
      pendR = Rcol;
      pendBase = Jt * BM;
    }
  }

  if (pend) flushcs();
  flushrs(Aprev, hprev);
}

// Dsame/Dcross hold acc = (1/tau)*log2e * s. exp(s/tau) = exp2(acc);
// -2*s = -ln2 * acc.  48 blocks x 256 threads = 12288 rows exactly.
__global__ void finalize1_kernel(const float* __restrict__ Rlow,
                                 const float* __restrict__ Rhigh,
                                 const float* __restrict__ Dsame,
                                 const float* __restrict__ Dcross,
                                 float* __restrict__ partial) {
  __shared__ float red[256];
  int k = blockIdx.x * 256 + threadIdx.x;
  float d1 = Rlow[k] + Rhigh[k] - EXP2F(Dsame[k]);
  float d2 = Rhigh[NROWS + k] + Rlow[NROWS + k] - EXP2F(Dsame[NROWS + k]);
  float acc = 0.5f * (logf(d1) + logf(d2)) - LN2F * Dcross[k];
  red[threadIdx.x] = acc;
  __syncthreads();
  for (int s = 128; s > 0; s >>= 1) {
    if (threadIdx.x < s) red[threadIdx.x] += red[threadIdx.x + s];
    __syncthreads();
  }
  if (threadIdx.x == 0) partial[blockIdx.x] = red[0];
}

__global__ void finalize2_kernel(const float* __restrict__ partial,
                                 float* __restrict__ out) {
  float x = (threadIdx.x < FB) ? partial[threadIdx.x] : 0.f;
#pragma unroll
  for (int s = 32; s > 0; s >>= 1) x += __shfl_down(x, s, 64);
  if (threadIdx.x == 0) out[0] = x / (float)NROWS;
}

// ---------------------------------------------------------------------------
extern "C" void kernel_launch(void* const* d_in, const int* in_sizes, int n_in,
                              void* d_out, int out_size, void* d_ws,
                              size_t ws_size, hipStream_t stream) {
  const float* z1 = (const float*)d_in[0];
  const float* z2 = (const float*)d_in[1];
  const float* W1 = (const float*)d_in[2];
  const float* b1 = (const float*)d_in[3];
  const float* W2 = (const float*)d_in[4];
  const float* b2 = (const float*)d_in[5];
  float* out = (float*)d_out;

  char* ws = (char*)d_ws;
  size_t off = 0;
  auto alloc = [&](size_t bytes) -> void* {
    void* p = ws + off;
    off += (bytes + 255) & ~(size_t)255;
    return p;
  };
  __bf16* Zb   = (__bf16*)alloc((size_t)TWO_N * KDIM * 2); // reused as Nq
  __bf16* W1b  = (__bf16*)alloc((size_t)KDIM * KDIM * 2);
  __bf16* W2b  = (__bf16*)alloc((size_t)KDIM * KDIM * 2);
  __bf16* Tb   = (__bf16*)alloc((size_t)TWO_N * KDIM * 2);
  float*  Rlow = (float*)alloc((size_t)TWO_N * 4);   // Rlow+Rhigh contiguous
  float*  Rhigh= (float*)alloc((size_t)TWO_N * 4);
  float*  Dsame= (float*)alloc((size_t)TWO_N * 4);
  float*  Dcross=(float*)alloc((size_t)NROWS * 4);
  float*  partial=(float*)alloc((size_t)FB * 4);
  uchar*  Nq = (uchar*)Zb;  // Zb dead after proj1; fp8 fits in its footprint

  // Rlow/Rhigh are adjacent 256-aligned allocations (TWO_N*4 = 98304 B each)
  hipMemsetAsync(Rlow, 0, (size_t)2 * TWO_N * 4, stream);

  int n4z = NROWS * KDIM / 4;   // 786432
  int n4w = KDIM * KDIM / 4;    // 16384
  int n4all = 2 * n4z + 2 * n4w;
  cast_all_kernel<<<(n4all + 255) / 256, 256, 0, stream>>>(z1, z2, W1, W2, Zb,
                                                           W1b, W2b);

  proj1_kernel<<<dim3(TWO_N / BM, KDIM / BN), 256, 0, stream>>>(Zb, W1b, b1, Tb);
  proj2norm_kernel<<<TWO_N / 64, 256, 0, stream>>>(Tb, W2b, b2, Nq);

  sim_kernel<<<PAIRS * SLOTS, 256, 0, stream>>>(Nq, Rlow, Rhigh, Dsame,
                                                Dcross);
  finalize1_kernel<<<FB, 256, 0, stream>>>(Rlow, Rhigh, Dsame, Dcross, partial);
  finalize2_kernel<<<1, 64, 0, stream>>>(partial, out);
}

// Round 12
// 210.190 us; speedup vs baseline: 1.3691x; 1.0295x over previous
//
#include <hip/hip_runtime.h>
#include <hip/hip_bf16.h>
#include <hip/hip_fp8.h>

// ---------------------------------------------------------------------------
// GRACE contrastive loss, MI355X.
//  out = mean_k 0.5*(ln d1_k + ln d2_k) - 2*s12[k,k]
// With M=[n1;n2] (24576x256) everything is row sums of exp(M M^T / tau)
// split by j-half, plus diagonal probes. S symmetric -> upper-triangle
// tiles only, row-sums + col-sums per tile (R12), col-sums deferred one
// tile (R13).
//
// R18: WHOLE-MLP FUSION. R17 ledger: sim 125us (structural floor after 7
// attempts), non-sim 91.6us for 6.4 GFLOP of GEMM (~3us of MFMA) —
// launch/roundtrip bound. Each 64-row output band depends only on the
// same 64 z-rows, so ONE kernel carries them end-to-end: GEMM1 (z read
// f32 directly, cvt during staging, z-prefetch pipelined one ks ahead) ->
// ELU -> T in LDS (32KB, read_frag swizzle: global 8-col block g of row r
// lives at LDS block g^(r&3)) -> GEMM2 (W2 staged per ks) -> SS shfl +
// cross-wave LDS reduce -> rsqrt*SIMSCALE -> fp8 -> Nq. Eliminates Zb and
// Tb (50MB traffic), 2 launches; GEMM1(block n) overlaps GEMM2(block m).
// Weights cast by a tiny kernel. LDS 53.3KB; per-phase register shape =
// proven proj kernels (~115). sim/finalize = R13/R17 verbatim.
// Tripwire: mlp WRITE >> 6.5MB = spill; absmax fail = T-swizzle bug.
// ---------------------------------------------------------------------------

#define NROWS 12288
#define TWO_N 24576
#define KDIM 256
#define BM 128
#define BK 32
#define NTILE 192   /* 24576 / 128 row-tiles */
#define PAIRS 96
#define SLOTS 16
#define FB 48                   /* finalize partial blocks */
#define LOG2E 1.4426950408889634f
#define SIMSCALE 1.6986436f     /* sqrt(2*log2(e)); acc = (1/tau)*log2e*s */
#define LN2F 0.6931471805599453f

#if __has_builtin(__builtin_amdgcn_exp2f)
#define EXP2F(x) __builtin_amdgcn_exp2f(x)
#else
#define EXP2F(x) exp2f(x)
#endif

typedef __bf16 bf16x8 __attribute__((ext_vector_type(8)));
typedef __bf16 bf16x4v __attribute__((ext_vector_type(4)));
typedef float f32x4 __attribute__((ext_vector_type(4)));
typedef int i32x4 __attribute__((ext_vector_type(4)));
typedef int i32x8 __attribute__((ext_vector_type(8)));
typedef unsigned char uchar;

typedef const __attribute__((address_space(1))) void* gptr_t;
typedef __attribute__((address_space(3))) void* lptr_t;

// read MFMA A/B fragment from a [rows x 32] LDS slab with the XOR swizzle
// (global 8-col block g of row r stored at LDS block g^(r&3))
__device__ __forceinline__ bf16x8 read_frag(const __bf16* lds, int rowbase,
                                            int tile, int l) {
  int r = rowbase + tile * 16 + (l & 15);
  int q = l >> 4;
  int blk = q ^ (r & 3);
  return *(const bf16x8*)(lds + r * 32 + blk * 8);
}

// ---------------------------------------------------------------------------
// cast W1, W2 to bf16 (z is consumed f32 directly by mlp_kernel)
__global__ void cast_w_kernel(const float* __restrict__ W1,
                              const float* __restrict__ W2,
                              __bf16* __restrict__ W1b,
                              __bf16* __restrict__ W2b) {
  const int n4w = KDIM * KDIM / 4;   // 16384
  int i = blockIdx.x * blockDim.x + threadIdx.x;
  const float* src;
  __bf16* dst;
  int j;
  if (i < n4w) {
    src = W1; dst = W1b; j = i;
  } else if (i < 2 * n4w) {
    src = W2; dst = W2b; j = i - n4w;
  } else {
    return;
  }
  float4 v = *(const float4*)(src + (size_t)j * 4);
  bf16x4v o;
  o[0] = (__bf16)v.x; o[1] = (__bf16)v.y; o[2] = (__bf16)v.z; o[3] = (__bf16)v.w;
  *(bf16x4v*)(dst + (size_t)j * 4) = o;
}

// fp8 e4m3 byte via the HW cvt (same rounding as R17)
__device__ __forceinline__ uchar fp8_byte(float x) {
#if __has_builtin(__builtin_amdgcn_cvt_pk_fp8_f32)
  int v = __builtin_amdgcn_cvt_pk_fp8_f32(x, 0.f, 0, false);
  return (uchar)(v & 0xFF);
#else
  __hip_fp8_e4m3 qv(x);
  return qv.__x;
#endif
}

// ======== R18 fused MLP: z -> T(LDS) -> H(regs) -> Nq ======================
// Block = 64 rows end-to-end (grid 384, 256 thr, 4 waves; wave w owns
// output cols w*64..w*64+63 in both GEMMs; rows shared by all waves).
__global__ __launch_bounds__(256, 2) void mlp_kernel(
    const float* __restrict__ z1, const float* __restrict__ z2,
    const __bf16* __restrict__ W1b, const __bf16* __restrict__ W2b,
    const float* __restrict__ b1, const float* __restrict__ b2,
    uchar* __restrict__ Nq) {
  __shared__ __align__(16) __bf16 Zs[64 * BK];       // 4 KB
  __shared__ __align__(16) __bf16 Ws[KDIM * BK];     // 16 KB
  __shared__ __align__(16) __bf16 Ts[8 * 64 * 32];   // 32 KB (8 ks-slabs)
  __shared__ float ssred[4][64];                     // 1 KB
  __shared__ float invred[64];
  uchar* qbuf = (uchar*)Ts;  // Ts dead after GEMM2; 16 KB reused
  int tid = threadIdx.x;
  int w = tid >> 6, l = tid & 63;
  int q = l >> 4, rx = l & 15;
  int i0 = blockIdx.x * 64;
  int wbcol = w * 64;
  const float* zrow = (i0 < NROWS) ? (z1 + (size_t)i0 * KDIM)
                                   : (z2 + (size_t)(i0 - NROWS) * KDIM);

  // stage one 256x32 weight slab into Ws (16 chunks of 16 rows, 4/wave)
  auto stageW = [&](const __bf16* Wb, int ks) {
#pragma unroll
    for (int t = 0; t < 4; ++t) {
      int c = w * 4 + t;
      int rr = l >> 2, c2 = l & 3;
      int r = c * 16 + rr;
      int src = c2 ^ (r & 3);
      const __bf16* ga = Wb + (size_t)r * KDIM + ks * BK + src * 8;
      __builtin_amdgcn_global_load_lds((gptr_t)ga, (lptr_t)(Ws + c * 512),
                                       16, 0, 0);
    }
  };
  // z fetch for slab ks: thread handles row tid>>2, dest 8-col block tid&3
  const int zr = tid >> 2, zblk = tid & 3;
  const int zsrc = zblk ^ (zr & 3);
  auto loadZ = [&](int ks, float4& v0, float4& v1) {
    const float* zp = zrow + (size_t)zr * KDIM + ks * BK + zsrc * 8;
    v0 = *(const float4*)zp;
    v1 = *(const float4*)(zp + 4);
  };

  // ---- GEMM1: T = ELU(Z @ W1^T + b1), Z cvt'd in-register ----
  f32x4 acc[4][4] = {};
  float4 zv0, zv1;
  loadZ(0, zv0, zv1);
  for (int ks = 0; ks < 8; ++ks) {
    __syncthreads();                 // prev Zs/Ws reads done
    bf16x8 zo;
    zo[0] = (__bf16)zv0.x; zo[1] = (__bf16)zv0.y;
    zo[2] = (__bf16)zv0.z; zo[3] = (__bf16)zv0.w;
    zo[4] = (__bf16)zv1.x; zo[5] = (__bf16)zv1.y;
    zo[6] = (__bf16)zv1.z; zo[7] = (__bf16)zv1.w;
    *(bf16x8*)(Zs + zr * 32 + zblk * 8) = zo;
    stageW(W1b, ks);
    if (ks + 1 < 8) loadZ(ks + 1, zv0, zv1);  // latency under MFMA phase
    __syncthreads();
    bf16x8 aF[4], bF[4];
#pragma unroll
    for (int mi = 0; mi < 4; ++mi) aF[mi] = read_frag(Zs, 0, mi, l);
#pragma unroll
    for (int ni = 0; ni < 4; ++ni) bF[ni] = read_frag(Ws, wbcol, ni, l);
#pragma unroll
    for (int mi = 0; mi < 4; ++mi)
#pragma unroll
      for (int ni = 0; ni < 4; ++ni)
        acc[mi][ni] = __builtin_amdgcn_mfma_f32_16x16x32_bf16(
            aF[mi], bF[ni], acc[mi][ni], 0, 0, 0);
  }

  // ---- bias1 + ELU -> Ts (swizzled so read_frag works per ks-slab) ----
  float bias1[4];
#pragma unroll
  for (int ni = 0; ni < 4; ++ni) bias1[ni] = b1[wbcol + ni * 16 + rx];
#pragma unroll
  for (int mi = 0; mi < 4; ++mi)
#pragma unroll
    for (int ni = 0; ni < 4; ++ni)
#pragma unroll
      for (int v = 0; v < 4; ++v) {
        int row = mi * 16 + q * 4 + v;
        int col = wbcol + ni * 16 + rx;
        float x = acc[mi][ni][v] + bias1[ni];
        x = x > 0.f ? x : (EXP2F(x * LOG2E) - 1.f);  // ELU
        int ks2 = col >> 5, c32 = col & 31;
        Ts[ks2 * 2048 + row * 32 + (((c32 >> 3) ^ (row & 3)) << 3) +
           (col & 7)] = (__bf16)x;
      }

  // ---- GEMM2: H = T @ W2^T + b2 (T from LDS; H stays in regs) ----
#pragma unroll
  for (int mi = 0; mi < 4; ++mi)
#pragma unroll
    for (int ni = 0; ni < 4; ++ni) acc[mi][ni] = (f32x4){0.f, 0.f, 0.f, 0.f};
  for (int ks = 0; ks < 8; ++ks) {
    __syncthreads();                 // T writes visible / prev Ws reads done
    stageW(W2b, ks);
    __syncthreads();
    bf16x8 aF[4], bF[4];
#pragma unroll
    for (int mi = 0; mi < 4; ++mi)
      aF[mi] = read_frag(Ts + ks * 2048, 0, mi, l);
#pragma unroll
    for (int ni = 0; ni < 4; ++ni) bF[ni] = read_frag(Ws, wbcol, ni, l);
#pragma unroll
    for (int mi = 0; mi < 4; ++mi)
#pragma unroll
      for (int ni = 0; ni < 4; ++ni)
        acc[mi][ni] = __builtin_amdgcn_mfma_f32_16x16x32_bf16(
            aF[mi], bF[ni], acc[mi][ni], 0, 0, 0);
  }

  // ---- bias2 + per-row sum of squares ----
  float bias2[4];
#pragma unroll
  for (int ni = 0; ni < 4; ++ni) bias2[ni] = b2[wbcol + ni * 16 + rx];
  float ss[4][4] = {};
#pragma unroll
  for (int mi = 0; mi < 4; ++mi)
#pragma unroll
    for (int ni = 0; ni < 4; ++ni)
#pragma unroll
      for (int v = 0; v < 4; ++v) {
        float x = acc[mi][ni][v] + bias2[ni];
        acc[mi][ni][v] = x;
        ss[mi][v] += x * x;
      }
#pragma unroll
  for (int mi = 0; mi < 4; ++mi)
#pragma unroll
    for (int v = 0; v < 4; ++v) {
      float x = ss[mi][v];
      x += __shfl_xor(x, 1, 64);
      x += __shfl_xor(x, 2, 64);
      x += __shfl_xor(x, 4, 64);
      x += __shfl_xor(x, 8, 64);
      if (rx == 0) ssred[w][mi * 16 + q * 4 + v] = x;  // 64-col band partial
    }
  __syncthreads();   // also: last Ts reads done -> qbuf alias safe
  if (tid < 64)
    invred[tid] = rsqrtf(ssred[0][tid] + ssred[1][tid] + ssred[2][tid] +
                         ssred[3][tid]) * SIMSCALE;
  __syncthreads();

  // ---- quantize into qbuf (LDS), then coalesced uint2 store to Nq ----
#pragma unroll
  for (int mi = 0; mi < 4; ++mi)
#pragma unroll
    for (int v = 0; v < 4; ++v) {
      int row = mi * 16 + q * 4 + v;
      float iv = invred[row];
#pragma unroll
      for (int ni = 0; ni < 4; ++ni)
        qbuf[row * KDIM + wbcol + ni * 16 + rx] =
            fp8_byte(acc[mi][ni][v] * iv);
    }
  __syncthreads();
  size_t base = (size_t)i0 * KDIM;
#pragma unroll
  for (int it = 0; it < 8; ++it) {
    int idx = it * 2048 + tid * 8;
    *(uint2*)(Nq + base + idx) = *(const uint2*)(qbuf + idx);
  }
}

// ======== R13 sim kernel (verbatim — best: ~123-125us) =====================
__global__ __launch_bounds__(256, 2) void sim_kernel(
    const uchar* __restrict__ Nq, float* __restrict__ Rlow,
    float* __restrict__ Rhigh, float* __restrict__ Dsame,
    float* __restrict__ Dcross) {
  __shared__ __align__(16) uchar Bs[2][BM * KDIM];  // 2 x 32KB
  int tid = threadIdx.x;
  int w = tid >> 6, l = tid & 63;
  int q = l >> 4;
  int rx = l & 15;
  int b = blockIdx.x;
  int p = b >> 4;              // pair index 0..95
  int s = b & 15;              // slot within pair
  const int I1 = p, I2 = NTILE - 1 - p;
  const int L1 = NTILE - I1;   // seg1 length
  int fstart = (s == 0) ? 0 : 13 + (s - 1) * 12;
  int fend = fstart + ((s == 0) ? 13 : 12);
  int warow = (w >> 1) * 64;   // A rows of this wave
  int wbcol = (w & 1) * 64;    // B cols of this wave

  unsigned off0[8];
#pragma unroll
  for (int t = 0; t < 8; ++t) {
    int ch = w * 8 + t;
    int r = ch * 4 + (l >> 4);
    int c = l & 15;
    int src = c ^ (r & 15);
    off0[t] = (unsigned)(r * KDIM + src * 16);
  }
  auto jtile_of = [&](int F) { return (F < L1) ? (I1 + F) : (F - 1); };
  auto atile_of = [&](int F) { return (F < L1) ? I1 : I2; };

  auto stage = [&](int F, int bi) {
    unsigned jo = (unsigned)(jtile_of(F) * (BM * KDIM));
#pragma unroll
    for (int t = 0; t < 8; ++t) {
      const uchar* ga = Nq + (size_t)(jo + off0[t]);
      uchar* la = Bs[bi] + (w * 8 + t) * 1024;
      __builtin_amdgcn_global_load_lds((gptr_t)ga, (lptr_t)la, 16, 0, 0);
    }
  };

  i32x8 aF[4][2];
  auto load_aF = [&](int Atile) {
#pragma unroll
    for (int mi = 0; mi < 4; ++mi) {
      const uchar* ap = Nq +
          (size_t)(Atile * BM + warow + mi * 16 + rx) * KDIM + q * 32;
#pragma unroll
      for (int hf = 0; hf < 2; ++hf)
        aF[mi][hf] = *(const i32x8*)(ap + hf * 128);
    }
  };

  int rdo[2][2];
#pragma unroll
  for (int hf = 0; hf < 2; ++hf) {
    int kb = hf * 8 + 2 * q;
    rdo[hf][0] = (kb ^ rx) << 4;
    rdo[hf][1] = ((kb + 1) ^ rx) << 4;
  }

  f32x4 rs4[4] = {};
  f32x4 cs4[4];
  int pend = 0;
  float* pendR = nullptr;
  int pendBase = 0;

  auto flushrs = [&](int Atile, int h) {
    float* R = h ? Rhigh : Rlow;
#pragma unroll
    for (int mi = 0; mi < 4; ++mi)
#pragma unroll
      for (int v = 0; v < 4; ++v) {
        float x = rs4[mi][v];
        x += __shfl_xor(x, 1, 64);
        x += __shfl_xor(x, 2, 64);
        x += __shfl_xor(x, 4, 64);
        x += __shfl_xor(x, 8, 64);
        if (rx == 0)
          atomicAdd(&R[Atile * BM + warow + mi * 16 + q * 4 + v], x);
        rs4[mi][v] = 0.f;
      }
  };
  auto flushcs = [&]() {
#pragma unroll
    for (int nj = 0; nj < 4; ++nj) {
      float c = (cs4[nj][0] + cs4[nj][1]) + (cs4[nj][2] + cs4[nj][3]);
      c += __shfl_xor(c, 16, 64);
      c += __shfl_xor(c, 32, 64);
      if (q == 0)
        atomicAdd(&pendR[pendBase + wbcol + nj * 16 + rx], c);
    }
    pend = 0;
  };

  const f32x4 Z4 = {0.f, 0.f, 0.f, 0.f};

  int Aprev = atile_of(fstart);
  int hprev = (jtile_of(fstart) >= NTILE / 2) ? 1 : 0;
  load_aF(Aprev);
  stage(fstart, 0);

  for (int f = fstart; f < fend; ++f) {
    int bi = (f - fstart) & 1;
    __syncthreads();
    if (f + 1 < fend) stage(f + 1, bi ^ 1);
    if (pend) flushcs();

    int Atile = atile_of(f);
    int Jt = jtile_of(f);
    int h = (Jt >= NTILE / 2) ? 1 : 0;
    if (Atile != Aprev) {
      flushrs(Aprev, hprev);
      load_aF(Atile);
      Aprev = Atile;
      hprev = h;
    } else if (h != hprev) {
      flushrs(Aprev, hprev);
      hprev = h;
    }

    bool dsame = (Jt == Atile);
    bool dcross = (Jt == Atile + NTILE / 2);
    float* Rcol = (Atile >= NTILE / 2) ? Rhigh : Rlow;

    const uchar* bL = Bs[bi] + (size_t)(wbcol + rx) * KDIM;
    const uchar* p00 = bL + rdo[0][0];
    const uchar* p01 = bL + rdo[0][1];
    const uchar* p10 = bL + rdo[1][0];
    const uchar* p11 = bL + rdo[1][1];

#pragma unroll
    for (int nj = 0; nj < 4; ++nj) {
      const int no = nj * 4096;
      i32x8 bF0 = __builtin_shufflevector(*(const i32x4*)(p00 + no),
                                          *(const i32x4*)(p01 + no),
                                          0, 1, 2, 3, 4, 5, 6, 7);
      i32x8 bF1 = __builtin_shufflevector(*(const i32x4*)(p10 + no),
                                          *(const i32x4*)(p11 + no),
                                          0, 1, 2, 3, 4, 5, 6, 7);
      f32x4 acc[4];
#pragma unroll
      for (int mi = 0; mi < 4; ++mi)
        acc[mi] = __builtin_amdgcn_mfma_scale_f32_16x16x128_f8f6f4(
            aF[mi][0], bF0, Z4, 0, 0, 0, 0x7F7F7F7F, 0, 0x7F7F7F7F);
#pragma unroll
      for (int mi = 0; mi < 4; ++mi)
        acc[mi] = __builtin_amdgcn_mfma_scale_f32_16x16x128_f8f6f4(
            aF[mi][1], bF1, acc[mi], 0, 0, 0, 0x7F7F7F7F, 0, 0x7F7F7F7F);
#pragma unroll
      for (int mi = 0; mi < 4; ++mi) {
        f32x4 e4;
        e4[0] = EXP2F(acc[mi][0]);
        e4[1] = EXP2F(acc[mi][1]);
        e4[2] = EXP2F(acc[mi][2]);
        e4[3] = EXP2F(acc[mi][3]);
        rs4[mi] += e4;
        cs4[nj] = (mi == 0) ? e4 : (cs4[nj] + e4);
      }

      if (dsame | dcross) {
        float* D = dsame ? Dsame : Dcross;
#pragma unroll
        for (int mi = 0; mi < 4; ++mi)
#pragma unroll
          for (int v = 0; v < 4; ++v) {
            int li = warow + mi * 16 + q * 4 + v;
            int lj = wbcol + nj * 16 + rx;
            if (li == lj) D[Atile * BM + li] = acc[mi][v];
          }
      }
    }

    if (!dsame) {
      pend = 1;
      pendR = Rcol;
      pendBase = Jt * BM;
    }
  }

  if (pend) flushcs();
  flushrs(Aprev, hprev);
}

// Dsame/Dcross hold acc = (1/tau)*log2e * s. exp(s/tau) = exp2(acc);
// -2*s = -ln2 * acc.  48 blocks x 256 threads = 12288 rows exactly.
__global__ void finalize1_kernel(const float* __restrict__ Rlow,
                                 const float* __restrict__ Rhigh,
                                 const float* __restrict__ Dsame,
                                 const float* __restrict__ Dcross,
                                 float* __restrict__ partial) {
  __shared__ float red[256];
  int k = blockIdx.x * 256 + threadIdx.x;
  float d1 = Rlow[k] + Rhigh[k] - EXP2F(Dsame[k]);
  float d2 = Rhigh[NROWS + k] + Rlow[NROWS + k] - EXP2F(Dsame[NROWS + k]);
  float acc = 0.5f * (logf(d1) + logf(d2)) - LN2F * Dcross[k];
  red[threadIdx.x] = acc;
  __syncthreads();
  for (int s = 128; s > 0; s >>= 1) {
    if (threadIdx.x < s) red[threadIdx.x] += red[threadIdx.x + s];
    __syncthreads();
  }
  if (threadIdx.x == 0) partial[blockIdx.x] = red[0];
}

__global__ void finalize2_kernel(const float* __restrict__ partial,
                                 float* __restrict__ out) {
  float x = (threadIdx.x < FB) ? partial[threadIdx.x] : 0.f;
#pragma unroll
  for (int s = 32; s > 0; s >>= 1) x += __shfl_down(x, s, 64);
  if (threadIdx.x == 0) out[0] = x / (float)NROWS;
}

// ---------------------------------------------------------------------------
extern "C" void kernel_launch(void* const* d_in, const int* in_sizes, int n_in,
                              void* d_out, int out_size, void* d_ws,
                              size_t ws_size, hipStream_t stream) {
  const float* z1 = (const float*)d_in[0];
  const float* z2 = (const float*)d_in[1];
  const float* W1 = (const float*)d_in[2];
  const float* b1 = (const float*)d_in[3];
  const float* W2 = (const float*)d_in[4];
  const float* b2 = (const float*)d_in[5];
  float* out = (float*)d_out;

  char* ws = (char*)d_ws;
  size_t off = 0;
  auto alloc = [&](size_t bytes) -> void* {
    void* p = ws + off;
    off += (bytes + 255) & ~(size_t)255;
    return p;
  };
  __bf16* W1b  = (__bf16*)alloc((size_t)KDIM * KDIM * 2);
  __bf16* W2b  = (__bf16*)alloc((size_t)KDIM * KDIM * 2);
  uchar*  Nq   = (uchar*)alloc((size_t)TWO_N * KDIM);
  float*  Rlow = (float*)alloc((size_t)TWO_N * 4);   // Rlow+Rhigh contiguous
  float*  Rhigh= (float*)alloc((size_t)TWO_N * 4);
  float*  Dsame= (float*)alloc((size_t)TWO_N * 4);
  float*  Dcross=(float*)alloc((size_t)NROWS * 4);
  float*  partial=(float*)alloc((size_t)FB * 4);

  // Rlow/Rhigh are adjacent 256-aligned allocations (TWO_N*4 = 98304 B each)
  hipMemsetAsync(Rlow, 0, (size_t)2 * TWO_N * 4, stream);

  int n4w = KDIM * KDIM / 4;    // 16384
  cast_w_kernel<<<(2 * n4w + 255) / 256, 256, 0, stream>>>(W1, W2, W1b, W2b);

  mlp_kernel<<<TWO_N / 64, 256, 0, stream>>>(z1, z2, W1b, W2b, b1, b2, Nq);

  sim_kernel<<<PAIRS * SLOTS, 256, 0, stream>>>(Nq, Rlow, Rhigh, Dsame,
                                                Dcross);
  finalize1_kernel<<<FB, 256, 0, stream>>>(Rlow, Rhigh, Dsame, Dcross, partial);
  finalize2_kernel<<<1, 64, 0, stream>>>(partial, out);
}